// Round 4
// baseline (203.058 us; speedup 1.0000x reference)
//
#include <hip/hip_runtime.h>
#include <hip/hip_bf16.h>

// Problem constants (reference: N, E, K, F_IN, H = 50000, 640000, 3, 128, 128)
#define NN 50000
#define NE 640000
#define CAP 64          // bucket capacity; deg~Poisson(12.8), P(deg>=64)~5e-27
#define NGB 782         // gates blocks / dst bins: ceil(NN/64)
#define NBIN 782
#define NA 196          // bin-split blocks
#define EPA 3328        // edges per A-block (13*256); 196*3328 = 652288 >= NE
#define ORow 784        // offs row stride in ints (NBIN+1 rounded up)

typedef unsigned short ushort_t;
typedef unsigned int uint_t;
typedef __attribute__((ext_vector_type(8))) short bf16x8;   // 8 bf16 = 4 VGPRs
typedef __attribute__((ext_vector_type(4))) float f32x4;

__device__ __forceinline__ float b2f(ushort_t u) {
    union { uint_t u; float f; } v; v.u = ((uint_t)u) << 16; return v.f;
}
__device__ __forceinline__ ushort_t f2b(float f) {
    union { float f; uint_t u; } v; v.f = f;
    uint_t u = v.u;
    uint_t r = u + 0x7fffu + ((u >> 16) & 1u);   // round-nearest-even
    return (ushort_t)(r >> 16);
}
// fast transcendentals: v_exp + v_rcp (err ~1e-6, vs 4.9e-4 pipeline absmax)
__device__ __forceinline__ float fsig(float x)  { return __builtin_amdgcn_rcpf(1.0f + __expf(-x)); }
__device__ __forceinline__ float ftanh(float x) { return 1.0f - 2.0f * __builtin_amdgcn_rcpf(1.0f + __expf(2.0f * x)); }
// mode-aware scalar param load: mf=1 -> f32 array, mf=0 -> bf16 array
__device__ __forceinline__ float ldm(const void* p, int i, int mf) {
    return mf ? ((const float*)p)[i] : b2f(((const ushort_t*)p)[i]);
}

// ---- workspace layout (bytes), total 16.36 MB ----
// R16: cooperative launch failed in-harness (R15); same dep-graph repacked as
// 3 plain launches. K1: binsplit||prep (independent). K2: gates||cnt (cnt's
// LDS-atomic latency hides under MFMA). K3: rebuild buckets in LDS from chunk
// (2.6MB re-read) + gather own bin -> bsrc (12.8MB write + read-back) deleted.
// Zero device-scope atomics anywhere.
#define OFF_HB    0            // NN*128 bf16 (12,800,000)  raw h (post-gcn_w), bf16
#define OFF_CHUNK 12800000     // NA*EPA u32 (2,609,152)    bin-sorted packed edges
#define OFF_OFFS  15409152     // NA*ORow i32 (614,656)     per-(Ablock,bin) seg starts
#define OFF_CNT   16023808     // NN i32     (200,000)      in-degree
#define OFF_WT    16223808     // 4*16384 bf16 (131,072)    Wi^T, Wc^T, Wo^T, gcn_w^T
#define OFF_COEF  16354880     // 641 f32    (2,564)
#define OFF_MODE  16357444     // i32
#define WS_REQ    16357448

__global__ void fb_k(ushort_t* __restrict__ out, int n) {   // ws too small: diagnostic zeros
    int i = blockIdx.x * blockDim.x + threadIdx.x;
    if (i < n) out[i] = 0;
}

// ---------------------------------------------------------------------------
// K1: blocks 0..NA-1 bin-split; blocks NA..NA+32 prep (independent work).
// bin-split: LDS hist over 782 bins -> scan -> scatter packed
// (src<<6|dst&63) into the block's private chunk segment; per-(block,bin)
// segment starts -> offs. prep: transpose W_x[0],W_x[2],W_x[3],gcn_w ->
// bf16 WT [f][k]; block NA+32 folds biases/BN/linear into coef + publishes
// mode (f32-as-bf16 halves show exponents >= 0xC0; real bf16 N(0,1) never).
// ---------------------------------------------------------------------------
__launch_bounds__(256)
__global__ void bsprep_k(const ushort_t* __restrict__ x, const int* __restrict__ ei,
                         const void* __restrict__ Wx, const void* __restrict__ gcnw,
                         const void* __restrict__ wc, const void* __restrict__ bb,
                         const void* __restrict__ thb,
                         const void* __restrict__ gam, const void* __restrict__ bet,
                         const void* __restrict__ mea, const void* __restrict__ var,
                         const void* __restrict__ linw, const void* __restrict__ linb,
                         ushort_t* __restrict__ WT, float* __restrict__ coef,
                         int* __restrict__ mode,
                         uint_t* __restrict__ chunk, int* __restrict__ offs) {
    __shared__ int sh[1280];     // binsplit: hist [0,782) + scan [1024,1280); prep: detect [0,256)
    __shared__ float red[128];
    int b = blockIdx.x, t = threadIdx.x;

    if (b < NA) {                         // ---- bin-split ----
        int a = b;
        int e0 = a * EPA; if (e0 > NE) e0 = NE;
        int e1 = e0 + EPA; if (e1 > NE) e1 = NE;
        const int* dstp = ei + NE;
        for (int i = t; i < NBIN; i += 256) sh[i] = 0;
        __syncthreads();
        for (int i = e0 + t; i < e1; i += 256) atomicAdd(&sh[dstp[i] >> 6], 1);
        __syncthreads();
        int b0 = t * 4;
        int s = 0;
        #pragma unroll
        for (int j = 0; j < 4; j++) { int bi = b0 + j; if (bi < NBIN) s += sh[bi]; }
        sh[1024 + t] = s;
        __syncthreads();
        for (int off = 1; off < 256; off <<= 1) {       // inclusive scan
            int v = (t >= off) ? sh[1024 + t - off] : 0;
            __syncthreads();
            sh[1024 + t] += v;
            __syncthreads();
        }
        int run = (t == 0) ? 0 : sh[1024 + t - 1];
        int* orow = offs + a * ORow;
        #pragma unroll
        for (int j = 0; j < 4; j++) {
            int bi = b0 + j;
            if (bi < NBIN) {
                int c = sh[bi];
                orow[bi] = run;
                sh[bi] = run;             // hist slot becomes scatter cursor
                run += c;
            }
        }
        if (t == 0) orow[NBIN] = e1 - e0;
        __syncthreads();
        uint_t* ck = chunk + a * EPA;
        for (int i = e0 + t; i < e1; i += 256) {
            int d = dstp[i], sn = ei[i];
            int pos = atomicAdd(&sh[d >> 6], 1);
            ck[pos] = ((uint_t)sn << 6) | (uint_t)(d & 63);
        }
        return;
    }

    // ---- prep (self-computed mode) ----
    int bad = 0;
    for (int i = t; i < 4096; i += 256) {
        int e = (x[i] >> 7) & 0xFF;
        if (e >= 0xC0) bad++;
    }
    sh[t] = bad; __syncthreads();
    for (int o = 128; o >= 1; o >>= 1) { if (t < o) sh[t] += sh[t + o]; __syncthreads(); }
    int mf = (sh[0] > 8) ? 1 : 0;   // 1 = f32 inputs, 0 = bf16

    int wb = b - NA;
    if (wb < 32) {
        int gid = wb * 256 + t;         // 0..8191, 2048 threads/matrix
        int m  = gid >> 11;
        int u  = gid & 2047;
        int k  = u >> 4;
        int f0 = (u & 15) << 3;
        const int srcoff[4] = { 0, 2 * 16384, 3 * 16384, 0 };
        const void* S = (m == 3) ? gcnw : Wx;
        int sbase = srcoff[m] + k * 128 + f0;
        ushort_t vals[8];
        if (mf == 0) {
            bf16x8 v = *(const bf16x8*)((const ushort_t*)S + sbase);
            #pragma unroll
            for (int i = 0; i < 8; i++) vals[i] = (ushort_t)v[i];
        } else {
            const float* Sf = (const float*)S + sbase;
            #pragma unroll
            for (int i = 0; i < 8; i++) vals[i] = f2b(Sf[i]);
        }
        ushort_t* D = WT + m * 16384 + k;
        #pragma unroll
        for (int i = 0; i < 8; i++) D[(f0 + i) * 128] = vals[i];
    } else {
        if (t < 128) {
            float rs = rsqrtf(ldm(var, t, mf) + 1e-5f);
            float ga = ldm(gam, t, mf);
            float lw = ldm(linw, t, mf);
            coef[t]       = ldm(thb, t, mf)           + ldm(bb, t, mf);            // bias_i
            coef[128 + t] = ldm(thb, 2 * 128 + t, mf) + ldm(bb, 2 * 128 + t, mf);  // bias_c
            coef[256 + t] = ldm(thb, 3 * 128 + t, mf) + ldm(bb, 3 * 128 + t, mf);  // bias_o
            coef[384 + t] = ldm(wc, 2 * 128 + t, mf);                              // w_c[2]
            coef[512 + t] = ga * rs * lw;                                          // s[f]
            red[t] = (ldm(bet, t, mf) - ldm(mea, t, mf) * ga * rs) * lw;
        }
        __syncthreads();
        for (int off = 64; off >= 1; off >>= 1) {
            if (t < off && t < 128) red[t] += red[t + off];
            __syncthreads();
        }
        if (t == 0) {
            coef[640] = red[0] + ldm(linb, 0, mf);                                 // C
            mode[0] = mf;
        }
    }
}

// ---------------------------------------------------------------------------
// K2: 2*NGB blocks, even -> gates GEMM (bin b/2), odd -> per-bin in-degree
// count (bin b/2). Interleaved so cnt's latency-bound LDS-atomic work hides
// under gates' MFMA (R12 technique, with cnt instead of atomic-fill).
//   gates: one block = 4 waves = 64 nodes; wave w owns feature cols
//   [32w,32w+32) for all rows. MFMA f32_16x16x32_bf16 layouts (HW-verified):
//   A: a[j]=A[m=lane&15][k=(lane>>4)*8+j];  B: b[j]=B[k=(lane>>4)*8+j][n=lane&15]
//   D: reg r -> row (lane>>4)*4+r, col lane&15
//   cnt: gather bin's chunk segments, LDS histogram over 64 node counters,
//   write cnt (200KB total) coalesced.
// ---------------------------------------------------------------------------
__launch_bounds__(256)
__global__ void gacnt_k(const void* __restrict__ x, const ushort_t* __restrict__ WT,
                        const float* __restrict__ coef, const int* __restrict__ mode,
                        ushort_t* __restrict__ hb,
                        const uint_t* __restrict__ chunk, const int* __restrict__ offs,
                        int* __restrict__ cnt) {
    __shared__ __align__(16) char smem[17408];
    int b = blockIdx.x, t = threadIdx.x;

    if (b & 1) {                          // ---- cnt path ----
        int bin = b >> 1;
        int* P      = (int*)smem;               // [0,1024)
        int* sstart = (int*)(smem + 1024);      // 196 ints
        int* lcnt   = (int*)(smem + 1808);      // 64 ints
        if (t < 64) lcnt[t] = 0;
        int len = 0;
        if (t < NA) {
            int st = offs[t * ORow + bin];
            int en = offs[t * ORow + bin + 1];
            sstart[t] = st;
            len = en - st;
        }
        P[t] = len;
        __syncthreads();
        for (int off = 1; off < 256; off <<= 1) {     // inclusive scan of seg lens
            int v = (t >= off) ? P[t - off] : 0;
            __syncthreads();
            P[t] += v;
            __syncthreads();
        }
        int T = P[255];
        for (int i = t; i < T; i += 256) {
            int lo = 0, hi = NA - 1;                  // first a with P[a] > i
            while (lo < hi) { int mid = (lo + hi) >> 1; if (P[mid] > i) hi = mid; else lo = mid + 1; }
            int prev = (lo == 0) ? 0 : P[lo - 1];
            uint_t w = chunk[lo * EPA + sstart[lo] + (i - prev)];
            atomicAdd(&lcnt[(int)(w & 63u)], 1);
        }
        __syncthreads();
        if (t < 64) { int node = (bin << 6) + t; if (node < NN) cnt[node] = lcnt[t]; }
        return;
    }

    // ---- gates path ----
    ushort_t* tile = (ushort_t*)smem;     // [64][136], +8 pad (272B row stride)
    int gb = b >> 1;
    int base = gb * 64;
    int mf = mode[0];

    for (int i = 0; i < 4; i++) {
        int idx = (i * 256 + t) * 8;
        int row = idx >> 7, col = idx & 127;
        int n = base + row;
        bf16x8 v;
        if (n >= NN) {
            v = (bf16x8)0;
        } else if (mf == 0) {
            v = *(const bf16x8*)((const ushort_t*)x + n * 128 + col);
        } else {
            const float* xf = (const float*)x + n * 128 + col;
            float4 lo = *(const float4*)xf;
            float4 hi = *(const float4*)(xf + 4);
            v[0] = (short)f2b(lo.x); v[1] = (short)f2b(lo.y);
            v[2] = (short)f2b(lo.z); v[3] = (short)f2b(lo.w);
            v[4] = (short)f2b(hi.x); v[5] = (short)f2b(hi.y);
            v[6] = (short)f2b(hi.z); v[7] = (short)f2b(hi.w);
        }
        *(bf16x8*)&tile[row * 136 + col] = v;
    }
    __syncthreads();

    int lane = t & 63, wave = t >> 6;
    int m = lane & 15, quad = lane >> 4;

    bf16x8 a[4][4];
    #pragma unroll
    for (int rt = 0; rt < 4; rt++)
        #pragma unroll
        for (int kt = 0; kt < 4; kt++)
            a[rt][kt] = *(const bf16x8*)&tile[(rt * 16 + m) * 136 + kt * 32 + quad * 8];
    __syncthreads();   // all x reads done before Hs overwrites tile

    const ushort_t* WTi = WT;
    const ushort_t* WTc = WT + 16384;
    const ushort_t* WTo = WT + 2 * 16384;

    #pragma unroll
    for (int ft = 0; ft < 2; ft++) {
        int f = wave * 32 + ft * 16 + m;
        bf16x8 bi[4], bc[4], bo[4];
        #pragma unroll
        for (int kt = 0; kt < 4; kt++) {
            int off = f * 128 + kt * 32 + quad * 8;
            bi[kt] = *(const bf16x8*)(WTi + off);
            bc[kt] = *(const bf16x8*)(WTc + off);
            bo[kt] = *(const bf16x8*)(WTo + off);
        }
        float bi_f = coef[f], bc_f = coef[128 + f], bo_f = coef[256 + f], w2 = coef[384 + f];
        #pragma unroll
        for (int rt = 0; rt < 4; rt++) {
            f32x4 ai = {0,0,0,0}, ac = {0,0,0,0}, ao = {0,0,0,0};
            #pragma unroll
            for (int kt = 0; kt < 4; kt++) {
                ai = __builtin_amdgcn_mfma_f32_16x16x32_bf16(a[rt][kt], bi[kt], ai, 0, 0, 0);
                ac = __builtin_amdgcn_mfma_f32_16x16x32_bf16(a[rt][kt], bc[kt], ac, 0, 0, 0);
                ao = __builtin_amdgcn_mfma_f32_16x16x32_bf16(a[rt][kt], bo[kt], ao, 0, 0, 0);
            }
            #pragma unroll
            for (int r = 0; r < 4; r++) {
                float I  = fsig(ai[r] + bi_f);
                float T  = ftanh(ac[r] + bc_f);
                float Cs = I * T;                       // F*C_prev = 0
                float O  = fsig(ao[r] + w2 * Cs + bo_f);
                float Hs = O * ftanh(Cs);
                tile[(rt * 16 + quad * 4 + r) * 136 + f] = f2b(Hs);
            }
        }
    }
    __syncthreads();   // Hs tile complete (col-partitioned across waves)

    const ushort_t* WTg = WT + 3 * 16384;
    bf16x8 ah[4][4];
    #pragma unroll
    for (int rt = 0; rt < 4; rt++)
        #pragma unroll
        for (int kt = 0; kt < 4; kt++)
            ah[rt][kt] = *(const bf16x8*)&tile[(rt * 16 + m) * 136 + kt * 32 + quad * 8];

    #pragma unroll
    for (int ft = 0; ft < 2; ft++) {
        int f = wave * 32 + ft * 16 + m;
        bf16x8 bg[4];
        #pragma unroll
        for (int kt = 0; kt < 4; kt++)
            bg[kt] = *(const bf16x8*)(WTg + f * 128 + kt * 32 + quad * 8);
        #pragma unroll
        for (int rt = 0; rt < 4; rt++) {
            f32x4 acc = {0,0,0,0};
            #pragma unroll
            for (int kt = 0; kt < 4; kt++)
                acc = __builtin_amdgcn_mfma_f32_16x16x32_bf16(ah[rt][kt], bg[kt], acc, 0, 0, 0);
            #pragma unroll
            for (int r = 0; r < 4; r++) {
                int n = base + rt * 16 + quad * 4 + r;
                if (n < NN) hb[n * 128 + f] = f2b(acc[r]);   // RAW h (no dg pre-scale)
            }
        }
    }
}

// ---------------------------------------------------------------------------
// K3: one block per bin. Rebuild the bin's buckets in LDS from chunk (LDS
// atomics; 2.6MB re-read replaces the 25.6MB bsrc round-trip), then gather
// the block's own 64 dst nodes straight from LDS buckets:
// g[d] = dg[d]*(sum_e dg[s]*h[s] + dg[d]*h[d]) -> relu -> BN -> linear -> out.
// dg[s] from L2-resident cnt (written by K2); dg[d] from local lcnt.
// ---------------------------------------------------------------------------
__launch_bounds__(256)
__global__ void sgat_k(const uint_t* __restrict__ chunk, const int* __restrict__ offs,
                       const ushort_t* __restrict__ hb, const int* __restrict__ cnt,
                       const void* __restrict__ gcnb, const float* __restrict__ coef,
                       const int* __restrict__ mode, void* __restrict__ out) {
    __shared__ __align__(16) char smem[18448];
    int* P      = (int*)smem;               // [0,1024)
    int* sstart = (int*)(smem + 1024);      // 196 ints
    int* lcnt   = (int*)(smem + 1808);      // 64 ints
    uint_t* lbuck = (uint_t*)(smem + 2064); // 64*CAP u32 = 16 KB
    int b = blockIdx.x, t = threadIdx.x;
    int node0 = b << 6;

    if (t < 64) lcnt[t] = 0;
    int len = 0;
    if (t < NA) {
        int st = offs[t * ORow + b];
        int en = offs[t * ORow + b + 1];
        sstart[t] = st;
        len = en - st;
    }
    P[t] = len;
    __syncthreads();
    for (int off = 1; off < 256; off <<= 1) {     // inclusive scan of seg lens
        int v = (t >= off) ? P[t - off] : 0;
        __syncthreads();
        P[t] += v;
        __syncthreads();
    }
    int T = P[255];
    for (int i = t; i < T; i += 256) {
        int lo = 0, hi = NA - 1;                  // first a with P[a] > i
        while (lo < hi) { int mid = (lo + hi) >> 1; if (P[mid] > i) hi = mid; else lo = mid + 1; }
        int prev = (lo == 0) ? 0 : P[lo - 1];
        uint_t w = chunk[lo * EPA + sstart[lo] + (i - prev)];
        int d6 = (int)(w & 63u);
        int sn = (int)(w >> 6);
        int p = atomicAdd(&lcnt[d6], 1);
        if (p < CAP) lbuck[(d6 << 6) + p] = (uint_t)sn;
    }
    __syncthreads();

    int mf = mode[0];
    int wave = t >> 6, lane = t & 63;
    int half = lane >> 5, sl = lane & 31;
    for (int q = 0; q < 16; q++) {
        int local = wave * 16 + q;
        int wid = node0 + local;
        if (wid >= NN) break;                     // uniform per wave
        int c = lcnt[local];
        int deg = (c < CAP) ? c : CAP;
        const uint_t* lb = lbuck + (local << 6);
        float a0 = 0.0f, a1 = 0.0f, a2 = 0.0f, a3 = 0.0f;
        for (int j = half; j < deg; j += 4) {
            int ok2 = (j + 2 < deg);
            int s0 = (int)lb[j];
            int s1 = (int)lb[ok2 ? j + 2 : j];    // dup read; masked accumulate
            int cs0 = cnt[s0];
            int cs1 = cnt[s1];
            uint2 r0 = *(const uint2*)(hb + s0 * 128 + sl * 4);
            uint2 r1 = *(const uint2*)(hb + s1 * 128 + sl * 4);
            float w0 = rsqrtf(1.0f + (float)cs0);
            float w1 = ok2 ? rsqrtf(1.0f + (float)cs1) : 0.0f;
            a0 += w0 * b2f((ushort_t)(r0.x & 0xffffu)) + w1 * b2f((ushort_t)(r1.x & 0xffffu));
            a1 += w0 * b2f((ushort_t)(r0.x >> 16))     + w1 * b2f((ushort_t)(r1.x >> 16));
            a2 += w0 * b2f((ushort_t)(r0.y & 0xffffu)) + w1 * b2f((ushort_t)(r1.y & 0xffffu));
            a3 += w0 * b2f((ushort_t)(r0.y >> 16))     + w1 * b2f((ushort_t)(r1.y >> 16));
        }
        float d = rsqrtf(1.0f + (float)c);
        if (half == 0) {                          // self term once (weight dg[d])
            uint2 r = *(const uint2*)(hb + wid * 128 + sl * 4);
            a0 += d * b2f((ushort_t)(r.x & 0xffffu));
            a1 += d * b2f((ushort_t)(r.x >> 16));
            a2 += d * b2f((ushort_t)(r.y & 0xffffu));
            a3 += d * b2f((ushort_t)(r.y >> 16));
        }
        // combine halves (same feats in lane l and l^32)
        a0 += __shfl_xor(a0, 32); a1 += __shfl_xor(a1, 32);
        a2 += __shfl_xor(a2, 32); a3 += __shfl_xor(a3, 32);
        int fb = sl * 4;
        float g0 = d * a0 + ldm(gcnb, fb,     mf);
        float g1 = d * a1 + ldm(gcnb, fb + 1, mf);
        float g2 = d * a2 + ldm(gcnb, fb + 2, mf);
        float g3 = d * a3 + ldm(gcnb, fb + 3, mf);
        float v = fmaxf(g0, 0.0f) * coef[512 + fb]
                + fmaxf(g1, 0.0f) * coef[512 + fb + 1]
                + fmaxf(g2, 0.0f) * coef[512 + fb + 2]
                + fmaxf(g3, 0.0f) * coef[512 + fb + 3];
        #pragma unroll
        for (int o = 32; o >= 1; o >>= 1) v += __shfl_down(v, o);   // sums both halves = 2x
        if (lane == 0) {
            float r = 0.5f * v + coef[640];
            if (mf) ((float*)out)[wid] = r;
            else    ((ushort_t*)out)[wid] = f2b(r);
        }
    }
}

extern "C" void kernel_launch(void* const* d_in, const int* in_sizes, int n_in,
                              void* d_out, int out_size, void* d_ws, size_t ws_size,
                              hipStream_t stream) {
    if (ws_size < (size_t)WS_REQ) {   // diagnostic: finite 0.088 failure, not NaN
        fb_k<<<(out_size + 255) / 256, 256, 0, stream>>>((ushort_t*)d_out, out_size);
        return;
    }
    const ushort_t* x = (const ushort_t*)d_in[0];
    const int*  ei   = (const int*)d_in[1];
    // d_in[2] edge_weight: unused (ChebConv of zero state collapses to bias)
    const void* Wx   = d_in[3];
    const void* wc   = d_in[4];
    const void* bb   = d_in[5];
    // d_in[6] theta: unused
    const void* thb  = d_in[7];
    const void* gcnw = d_in[8];
    const void* gcnb = d_in[9];
    const void* gam  = d_in[10];
    const void* bet  = d_in[11];
    const void* mea  = d_in[12];
    const void* var  = d_in[13];
    const void* linw = d_in[14];
    const void* linb = d_in[15];

    char* ws = (char*)d_ws;
    ushort_t* hb    = (ushort_t*)(ws + OFF_HB);
    uint_t*   chunk = (uint_t*)  (ws + OFF_CHUNK);
    int*      offs  = (int*)     (ws + OFF_OFFS);
    int*      cnt   = (int*)     (ws + OFF_CNT);
    ushort_t* WT    = (ushort_t*)(ws + OFF_WT);
    float*    coef  = (float*)   (ws + OFF_COEF);
    int*      mode  = (int*)     (ws + OFF_MODE);

    bsprep_k<<<NA + 33, 256, 0, stream>>>(x, ei, Wx, gcnw, wc, bb, thb,
                                          gam, bet, mea, var, linw, linb,
                                          WT, coef, mode, chunk, offs);
    gacnt_k<<<2 * NGB, 256, 0, stream>>>(x, WT, coef, mode, hb, chunk, offs, cnt);
    sgat_k<<<NBIN, 256, 0, stream>>>(chunk, offs, hb, cnt, gcnb, coef, mode, d_out);
}

// Round 5
// 182.073 us; speedup vs baseline: 1.1153x; 1.1153x over previous
//
#include <hip/hip_runtime.h>
#include <hip/hip_bf16.h>

// Problem constants (reference: N, E, K, F_IN, H = 50000, 640000, 3, 128, 128)
#define NN 50000
#define NE 640000
#define CAP 64          // bucket capacity; deg~Poisson(12.8), P(deg>=64)~5e-27
#define NGB 782         // gates blocks / dst bins: ceil(NN/64)
#define NBIN 782
#define NA 196          // bin-split blocks
#define EPA 3328        // edges per A-block (13*256); 196*3328 = 652288 >= NE
#define ORow 784        // offs row stride in ints (NBIN+1 rounded up)

typedef unsigned short ushort_t;
typedef unsigned int uint_t;
typedef __attribute__((ext_vector_type(8))) short bf16x8;   // 8 bf16 = 4 VGPRs
typedef __attribute__((ext_vector_type(4))) float f32x4;

__device__ __forceinline__ float b2f(ushort_t u) {
    union { uint_t u; float f; } v; v.u = ((uint_t)u) << 16; return v.f;
}
__device__ __forceinline__ ushort_t f2b(float f) {
    union { float f; uint_t u; } v; v.f = f;
    uint_t u = v.u;
    uint_t r = u + 0x7fffu + ((u >> 16) & 1u);   // round-nearest-even
    return (ushort_t)(r >> 16);
}
// fast transcendentals: v_exp + v_rcp (err ~1e-6, vs 4.9e-4 pipeline absmax)
__device__ __forceinline__ float fsig(float x)  { return __builtin_amdgcn_rcpf(1.0f + __expf(-x)); }
__device__ __forceinline__ float ftanh(float x) { return 1.0f - 2.0f * __builtin_amdgcn_rcpf(1.0f + __expf(2.0f * x)); }
// mode-aware scalar param load: mf=1 -> f32 array, mf=0 -> bf16 array
__device__ __forceinline__ float ldm(const void* p, int i, int mf) {
    return mf ? ((const float*)p)[i] : b2f(((const ushort_t*)p)[i]);
}

// ---- workspace layout (bytes), total 29.16 MB (known-good ceiling: 31.65 MB) ----
// R17: R16's fused gather was latency-starved (3128 waves, sgat=62us >= 60
// falsification). Recombine best-measured pieces: K1 binsplit||prep; K2
// gates||scat(bsrc) interleaved (scat's ~13us hides under MFMA); K3 gather
// back to one-wave-per-node (50K waves) with 4-edge-deep MLP per half-wave.
// Zero device-scope atomics anywhere.
#define OFF_HB    0            // NN*128 bf16 (12,800,000)  raw h (post-gcn_w), bf16
#define OFF_BSRC  12800000     // NN*CAP i32 (12,800,000)   buckets (garbage slots = 0)
#define OFF_CHUNK 25600000     // NA*EPA u32 (2,609,152)    bin-sorted packed edges
#define OFF_OFFS  28209152     // NA*ORow i32 (614,656)     per-(Ablock,bin) seg starts
#define OFF_CNT   28823808     // NN i32     (200,000)      in-degree
#define OFF_WT    29023808     // 4*16384 bf16 (131,072)    Wi^T, Wc^T, Wo^T, gcn_w^T
#define OFF_COEF  29154880     // 641 f32    (2,564)
#define OFF_MODE  29157444     // i32
#define WS_REQ    29157448

__global__ void fb_k(ushort_t* __restrict__ out, int n) {   // ws too small: diagnostic zeros
    int i = blockIdx.x * blockDim.x + threadIdx.x;
    if (i < n) out[i] = 0;
}

// ---------------------------------------------------------------------------
// K1: blocks 0..NA-1 bin-split; blocks NA..NA+32 prep (independent work).
// bin-split: LDS hist over 782 bins -> scan -> scatter packed
// (src<<6|dst&63) into the block's private chunk segment; per-(block,bin)
// segment starts -> offs. prep: transpose W_x[0],W_x[2],W_x[3],gcn_w ->
// bf16 WT [f][k]; block NA+32 folds biases/BN/linear into coef + publishes
// mode (f32-as-bf16 halves show exponents >= 0xC0; real bf16 N(0,1) never).
// ---------------------------------------------------------------------------
__launch_bounds__(256)
__global__ void bsprep_k(const ushort_t* __restrict__ x, const int* __restrict__ ei,
                         const void* __restrict__ Wx, const void* __restrict__ gcnw,
                         const void* __restrict__ wc, const void* __restrict__ bb,
                         const void* __restrict__ thb,
                         const void* __restrict__ gam, const void* __restrict__ bet,
                         const void* __restrict__ mea, const void* __restrict__ var,
                         const void* __restrict__ linw, const void* __restrict__ linb,
                         ushort_t* __restrict__ WT, float* __restrict__ coef,
                         int* __restrict__ mode,
                         uint_t* __restrict__ chunk, int* __restrict__ offs) {
    __shared__ int sh[1280];     // binsplit: hist [0,782) + scan [1024,1280); prep: detect [0,256)
    __shared__ float red[128];
    int b = blockIdx.x, t = threadIdx.x;

    if (b < NA) {                         // ---- bin-split ----
        int a = b;
        int e0 = a * EPA; if (e0 > NE) e0 = NE;
        int e1 = e0 + EPA; if (e1 > NE) e1 = NE;
        const int* dstp = ei + NE;
        for (int i = t; i < NBIN; i += 256) sh[i] = 0;
        __syncthreads();
        for (int i = e0 + t; i < e1; i += 256) atomicAdd(&sh[dstp[i] >> 6], 1);
        __syncthreads();
        int b0 = t * 4;
        int s = 0;
        #pragma unroll
        for (int j = 0; j < 4; j++) { int bi = b0 + j; if (bi < NBIN) s += sh[bi]; }
        sh[1024 + t] = s;
        __syncthreads();
        for (int off = 1; off < 256; off <<= 1) {       // inclusive scan
            int v = (t >= off) ? sh[1024 + t - off] : 0;
            __syncthreads();
            sh[1024 + t] += v;
            __syncthreads();
        }
        int run = (t == 0) ? 0 : sh[1024 + t - 1];
        int* orow = offs + a * ORow;
        #pragma unroll
        for (int j = 0; j < 4; j++) {
            int bi = b0 + j;
            if (bi < NBIN) {
                int c = sh[bi];
                orow[bi] = run;
                sh[bi] = run;             // hist slot becomes scatter cursor
                run += c;
            }
        }
        if (t == 0) orow[NBIN] = e1 - e0;
        __syncthreads();
        uint_t* ck = chunk + a * EPA;
        for (int i = e0 + t; i < e1; i += 256) {
            int d = dstp[i], sn = ei[i];
            int pos = atomicAdd(&sh[d >> 6], 1);
            ck[pos] = ((uint_t)sn << 6) | (uint_t)(d & 63);
        }
        return;
    }

    // ---- prep (self-computed mode) ----
    int bad = 0;
    for (int i = t; i < 4096; i += 256) {
        int e = (x[i] >> 7) & 0xFF;
        if (e >= 0xC0) bad++;
    }
    sh[t] = bad; __syncthreads();
    for (int o = 128; o >= 1; o >>= 1) { if (t < o) sh[t] += sh[t + o]; __syncthreads(); }
    int mf = (sh[0] > 8) ? 1 : 0;   // 1 = f32 inputs, 0 = bf16

    int wb = b - NA;
    if (wb < 32) {
        int gid = wb * 256 + t;         // 0..8191, 2048 threads/matrix
        int m  = gid >> 11;
        int u  = gid & 2047;
        int k  = u >> 4;
        int f0 = (u & 15) << 3;
        const int srcoff[4] = { 0, 2 * 16384, 3 * 16384, 0 };
        const void* S = (m == 3) ? gcnw : Wx;
        int sbase = srcoff[m] + k * 128 + f0;
        ushort_t vals[8];
        if (mf == 0) {
            bf16x8 v = *(const bf16x8*)((const ushort_t*)S + sbase);
            #pragma unroll
            for (int i = 0; i < 8; i++) vals[i] = (ushort_t)v[i];
        } else {
            const float* Sf = (const float*)S + sbase;
            #pragma unroll
            for (int i = 0; i < 8; i++) vals[i] = f2b(Sf[i]);
        }
        ushort_t* D = WT + m * 16384 + k;
        #pragma unroll
        for (int i = 0; i < 8; i++) D[(f0 + i) * 128] = vals[i];
    } else {
        if (t < 128) {
            float rs = rsqrtf(ldm(var, t, mf) + 1e-5f);
            float ga = ldm(gam, t, mf);
            float lw = ldm(linw, t, mf);
            coef[t]       = ldm(thb, t, mf)           + ldm(bb, t, mf);            // bias_i
            coef[128 + t] = ldm(thb, 2 * 128 + t, mf) + ldm(bb, 2 * 128 + t, mf);  // bias_c
            coef[256 + t] = ldm(thb, 3 * 128 + t, mf) + ldm(bb, 3 * 128 + t, mf);  // bias_o
            coef[384 + t] = ldm(wc, 2 * 128 + t, mf);                              // w_c[2]
            coef[512 + t] = ga * rs * lw;                                          // s[f]
            red[t] = (ldm(bet, t, mf) - ldm(mea, t, mf) * ga * rs) * lw;
        }
        __syncthreads();
        for (int off = 64; off >= 1; off >>= 1) {
            if (t < off && t < 128) red[t] += red[t + off];
            __syncthreads();
        }
        if (t == 0) {
            coef[640] = red[0] + ldm(linb, 0, mf);                                 // C
            mode[0] = mf;
        }
    }
}

// ---------------------------------------------------------------------------
// K2: 2*NGB blocks, even -> gates GEMM (bin b/2), odd -> scat (bin b/2).
// Interleaved so scat's latency-bound work hides under gates' MFMA.
//   gates: one block = 4 waves = 64 nodes; wave w owns feature cols
//   [32w,32w+32) for all rows. MFMA f32_16x16x32_bf16 layouts (HW-verified):
//   A: a[j]=A[m=lane&15][k=(lane>>4)*8+j];  B: b[j]=B[k=(lane>>4)*8+j][n=lane&15]
//   D: reg r -> row (lane>>4)*4+r, col lane&15
//   scat: gather bin's chunk segments, LDS-atomic slot assign into
//   zero-initialized LDS buckets, write bsrc (int4 coalesced) + cnt.
//   Zero-init => garbage slots hold src 0, safe for K3's speculative loads.
// ---------------------------------------------------------------------------
__launch_bounds__(256)
__global__ void gasc_k(const void* __restrict__ x, const ushort_t* __restrict__ WT,
                       const float* __restrict__ coef, const int* __restrict__ mode,
                       ushort_t* __restrict__ hb,
                       const uint_t* __restrict__ chunk, const int* __restrict__ offs,
                       int* __restrict__ bsrc, int* __restrict__ cnt) {
    __shared__ __align__(16) char smem[18448];
    int b = blockIdx.x, t = threadIdx.x;

    if (b & 1) {                          // ---- scat path ----
        int bin = b >> 1;
        int node0 = bin << 6;
        int* P      = (int*)smem;               // [0,1024)
        int* sstart = (int*)(smem + 1024);      // 196 ints
        int* lcnt   = (int*)(smem + 1808);      // 64 ints
        uint_t* lbuck = (uint_t*)(smem + 2064); // 64*CAP u32 = 16 KB
        if (t < 64) lcnt[t] = 0;
        for (int i = t; i < 64 * CAP; i += 256) lbuck[i] = 0;   // garbage slots -> src 0
        int len = 0;
        if (t < NA) {
            int st = offs[t * ORow + bin];
            int en = offs[t * ORow + bin + 1];
            sstart[t] = st;
            len = en - st;
        }
        P[t] = len;
        __syncthreads();
        for (int off = 1; off < 256; off <<= 1) {     // inclusive scan of seg lens
            int v = (t >= off) ? P[t - off] : 0;
            __syncthreads();
            P[t] += v;
            __syncthreads();
        }
        int T = P[255];
        for (int i = t; i < T; i += 256) {
            int lo = 0, hi = NA - 1;                  // first a with P[a] > i
            while (lo < hi) { int mid = (lo + hi) >> 1; if (P[mid] > i) hi = mid; else lo = mid + 1; }
            int prev = (lo == 0) ? 0 : P[lo - 1];
            uint_t w = chunk[lo * EPA + sstart[lo] + (i - prev)];
            int d6 = (int)(w & 63u);
            int sn = (int)(w >> 6);
            int p = atomicAdd(&lcnt[d6], 1);
            if (p < CAP) lbuck[(d6 << 6) + p] = (uint_t)sn;
        }
        __syncthreads();
        if (t < 64) { int node = node0 + t; if (node < NN) cnt[node] = lcnt[t]; }
        const int4* lb4 = (const int4*)lbuck;
        int4* bs4 = (int4*)bsrc;
        for (int i = t; i < 1024; i += 256) {         // 64 nodes * 64 slots / 4
            int node = node0 + (i >> 4);
            if (node < NN) bs4[(node0 << 4) + i] = lb4[i];
        }
        return;
    }

    // ---- gates path ----
    ushort_t* tile = (ushort_t*)smem;     // [64][136], +8 pad (272B row stride)
    int gb = b >> 1;
    int base = gb * 64;
    int mf = mode[0];

    for (int i = 0; i < 4; i++) {
        int idx = (i * 256 + t) * 8;
        int row = idx >> 7, col = idx & 127;
        int n = base + row;
        bf16x8 v;
        if (n >= NN) {
            v = (bf16x8)0;
        } else if (mf == 0) {
            v = *(const bf16x8*)((const ushort_t*)x + n * 128 + col);
        } else {
            const float* xf = (const float*)x + n * 128 + col;
            float4 lo = *(const float4*)xf;
            float4 hi = *(const float4*)(xf + 4);
            v[0] = (short)f2b(lo.x); v[1] = (short)f2b(lo.y);
            v[2] = (short)f2b(lo.z); v[3] = (short)f2b(lo.w);
            v[4] = (short)f2b(hi.x); v[5] = (short)f2b(hi.y);
            v[6] = (short)f2b(hi.z); v[7] = (short)f2b(hi.w);
        }
        *(bf16x8*)&tile[row * 136 + col] = v;
    }
    __syncthreads();

    int lane = t & 63, wave = t >> 6;
    int m = lane & 15, quad = lane >> 4;

    bf16x8 a[4][4];
    #pragma unroll
    for (int rt = 0; rt < 4; rt++)
        #pragma unroll
        for (int kt = 0; kt < 4; kt++)
            a[rt][kt] = *(const bf16x8*)&tile[(rt * 16 + m) * 136 + kt * 32 + quad * 8];
    __syncthreads();   // all x reads done before Hs overwrites tile

    const ushort_t* WTi = WT;
    const ushort_t* WTc = WT + 16384;
    const ushort_t* WTo = WT + 2 * 16384;

    #pragma unroll
    for (int ft = 0; ft < 2; ft++) {
        int f = wave * 32 + ft * 16 + m;
        bf16x8 bi[4], bc[4], bo[4];
        #pragma unroll
        for (int kt = 0; kt < 4; kt++) {
            int off = f * 128 + kt * 32 + quad * 8;
            bi[kt] = *(const bf16x8*)(WTi + off);
            bc[kt] = *(const bf16x8*)(WTc + off);
            bo[kt] = *(const bf16x8*)(WTo + off);
        }
        float bi_f = coef[f], bc_f = coef[128 + f], bo_f = coef[256 + f], w2 = coef[384 + f];
        #pragma unroll
        for (int rt = 0; rt < 4; rt++) {
            f32x4 ai = {0,0,0,0}, ac = {0,0,0,0}, ao = {0,0,0,0};
            #pragma unroll
            for (int kt = 0; kt < 4; kt++) {
                ai = __builtin_amdgcn_mfma_f32_16x16x32_bf16(a[rt][kt], bi[kt], ai, 0, 0, 0);
                ac = __builtin_amdgcn_mfma_f32_16x16x32_bf16(a[rt][kt], bc[kt], ac, 0, 0, 0);
                ao = __builtin_amdgcn_mfma_f32_16x16x32_bf16(a[rt][kt], bo[kt], ao, 0, 0, 0);
            }
            #pragma unroll
            for (int r = 0; r < 4; r++) {
                float I  = fsig(ai[r] + bi_f);
                float T  = ftanh(ac[r] + bc_f);
                float Cs = I * T;                       // F*C_prev = 0
                float O  = fsig(ao[r] + w2 * Cs + bo_f);
                float Hs = O * ftanh(Cs);
                tile[(rt * 16 + quad * 4 + r) * 136 + f] = f2b(Hs);
            }
        }
    }
    __syncthreads();   // Hs tile complete (col-partitioned across waves)

    const ushort_t* WTg = WT + 3 * 16384;
    bf16x8 ah[4][4];
    #pragma unroll
    for (int rt = 0; rt < 4; rt++)
        #pragma unroll
        for (int kt = 0; kt < 4; kt++)
            ah[rt][kt] = *(const bf16x8*)&tile[(rt * 16 + m) * 136 + kt * 32 + quad * 8];

    #pragma unroll
    for (int ft = 0; ft < 2; ft++) {
        int f = wave * 32 + ft * 16 + m;
        bf16x8 bg[4];
        #pragma unroll
        for (int kt = 0; kt < 4; kt++)
            bg[kt] = *(const bf16x8*)(WTg + f * 128 + kt * 32 + quad * 8);
        #pragma unroll
        for (int rt = 0; rt < 4; rt++) {
            f32x4 acc = {0,0,0,0};
            #pragma unroll
            for (int kt = 0; kt < 4; kt++)
                acc = __builtin_amdgcn_mfma_f32_16x16x32_bf16(ah[rt][kt], bg[kt], acc, 0, 0, 0);
            #pragma unroll
            for (int r = 0; r < 4; r++) {
                int n = base + rt * 16 + quad * 4 + r;
                if (n < NN) hb[n * 128 + f] = f2b(acc[r]);   // RAW h (no dg pre-scale)
            }
        }
    }
}

// ---------------------------------------------------------------------------
// K3: fused gather + self-loop + relu->BN->linear. One wave per destination
// (50K waves -> full occupancy, deep TLP). R17: 4 edges in flight per
// half-wave (stride-8 unroll); invalid slots are zero-filled (src 0) so
// loads issue unconditionally and the tail is masked by w=0 -- row 0 stays
// L1-hot, masked loads are nearly free. dg[s] from L2-resident cnt.
// g[d] = dg[d]*(sum_e dg[s]*h[s] + dg[d]*h[d])
// ---------------------------------------------------------------------------
__launch_bounds__(256)
__global__ void gat_out_k(const ushort_t* __restrict__ hb, const int* __restrict__ cnt,
                          const int* __restrict__ bsrc,
                          const void* __restrict__ gcnb, const float* __restrict__ coef,
                          const int* __restrict__ mode, void* __restrict__ out) {
    int wid  = (blockIdx.x * blockDim.x + threadIdx.x) >> 6;
    int lane = threadIdx.x & 63;
    if (wid >= NN) return;
    int half = lane >> 5, sl = lane & 31;
    int c = cnt[wid]; if (c < 0) c = 0;
    int deg = (c < CAP) ? c : CAP;
    const int* brow = bsrc + wid * CAP;

    float a0 = 0.0f, a1 = 0.0f, a2 = 0.0f, a3 = 0.0f;
    for (int j = half; j < deg; j += 8) {
        int i1 = j + 2, i2 = j + 4, i3 = j + 6;
        int s0 = brow[j];
        int s1 = brow[i1 & (CAP - 1)];    // in-bounds; value 0 if beyond fill
        int s2 = brow[i2 & (CAP - 1)];
        int s3 = brow[i3 & (CAP - 1)];
        int c0 = cnt[s0], c1 = cnt[s1], c2 = cnt[s2], c3 = cnt[s3];
        uint2 r0 = *(const uint2*)(hb + s0 * 128 + sl * 4);
        uint2 r1 = *(const uint2*)(hb + s1 * 128 + sl * 4);
        uint2 r2 = *(const uint2*)(hb + s2 * 128 + sl * 4);
        uint2 r3 = *(const uint2*)(hb + s3 * 128 + sl * 4);
        float w0 = rsqrtf(1.0f + (float)c0);
        float w1 = (i1 < deg) ? rsqrtf(1.0f + (float)c1) : 0.0f;
        float w2 = (i2 < deg) ? rsqrtf(1.0f + (float)c2) : 0.0f;
        float w3 = (i3 < deg) ? rsqrtf(1.0f + (float)c3) : 0.0f;
        a0 += w0 * b2f((ushort_t)(r0.x & 0xffffu)) + w1 * b2f((ushort_t)(r1.x & 0xffffu))
            + w2 * b2f((ushort_t)(r2.x & 0xffffu)) + w3 * b2f((ushort_t)(r3.x & 0xffffu));
        a1 += w0 * b2f((ushort_t)(r0.x >> 16))     + w1 * b2f((ushort_t)(r1.x >> 16))
            + w2 * b2f((ushort_t)(r2.x >> 16))     + w3 * b2f((ushort_t)(r3.x >> 16));
        a2 += w0 * b2f((ushort_t)(r0.y & 0xffffu)) + w1 * b2f((ushort_t)(r1.y & 0xffffu))
            + w2 * b2f((ushort_t)(r2.y & 0xffffu)) + w3 * b2f((ushort_t)(r3.y & 0xffffu));
        a3 += w0 * b2f((ushort_t)(r0.y >> 16))     + w1 * b2f((ushort_t)(r1.y >> 16))
            + w2 * b2f((ushort_t)(r2.y >> 16))     + w3 * b2f((ushort_t)(r3.y >> 16));
    }
    float d = rsqrtf(1.0f + (float)c);
    if (half == 0) {                       // self term once (weight dg[d], pre-combine)
        uint2 r = *(const uint2*)(hb + wid * 128 + sl * 4);
        a0 += d * b2f((ushort_t)(r.x & 0xffffu));
        a1 += d * b2f((ushort_t)(r.x >> 16));
        a2 += d * b2f((ushort_t)(r.y & 0xffffu));
        a3 += d * b2f((ushort_t)(r.y >> 16));
    }
    // combine halves (same feats in lane l and l^32)
    a0 += __shfl_xor(a0, 32); a1 += __shfl_xor(a1, 32);
    a2 += __shfl_xor(a2, 32); a3 += __shfl_xor(a3, 32);
    int mf = mode[0];
    int fb = sl * 4;
    float g0 = d * a0 + ldm(gcnb, fb,     mf);
    float g1 = d * a1 + ldm(gcnb, fb + 1, mf);
    float g2 = d * a2 + ldm(gcnb, fb + 2, mf);
    float g3 = d * a3 + ldm(gcnb, fb + 3, mf);
    float v = fmaxf(g0, 0.0f) * coef[512 + fb]
            + fmaxf(g1, 0.0f) * coef[512 + fb + 1]
            + fmaxf(g2, 0.0f) * coef[512 + fb + 2]
            + fmaxf(g3, 0.0f) * coef[512 + fb + 3];
    #pragma unroll
    for (int o = 32; o >= 1; o >>= 1) v += __shfl_down(v, o);   // sums both halves = 2x
    if (lane == 0) {
        float r = 0.5f * v + coef[640];
        if (mf) ((float*)out)[wid] = r;
        else    ((ushort_t*)out)[wid] = f2b(r);
    }
}

extern "C" void kernel_launch(void* const* d_in, const int* in_sizes, int n_in,
                              void* d_out, int out_size, void* d_ws, size_t ws_size,
                              hipStream_t stream) {
    if (ws_size < (size_t)WS_REQ) {   // diagnostic: finite 0.088 failure, not NaN
        fb_k<<<(out_size + 255) / 256, 256, 0, stream>>>((ushort_t*)d_out, out_size);
        return;
    }
    const ushort_t* x = (const ushort_t*)d_in[0];
    const int*  ei   = (const int*)d_in[1];
    // d_in[2] edge_weight: unused (ChebConv of zero state collapses to bias)
    const void* Wx   = d_in[3];
    const void* wc   = d_in[4];
    const void* bb   = d_in[5];
    // d_in[6] theta: unused
    const void* thb  = d_in[7];
    const void* gcnw = d_in[8];
    const void* gcnb = d_in[9];
    const void* gam  = d_in[10];
    const void* bet  = d_in[11];
    const void* mea  = d_in[12];
    const void* var  = d_in[13];
    const void* linw = d_in[14];
    const void* linb = d_in[15];

    char* ws = (char*)d_ws;
    ushort_t* hb    = (ushort_t*)(ws + OFF_HB);
    int*      bsrc  = (int*)     (ws + OFF_BSRC);
    uint_t*   chunk = (uint_t*)  (ws + OFF_CHUNK);
    int*      offs  = (int*)     (ws + OFF_OFFS);
    int*      cnt   = (int*)     (ws + OFF_CNT);
    ushort_t* WT    = (ushort_t*)(ws + OFF_WT);
    float*    coef  = (float*)   (ws + OFF_COEF);
    int*      mode  = (int*)     (ws + OFF_MODE);

    bsprep_k<<<NA + 33, 256, 0, stream>>>(x, ei, Wx, gcnw, wc, bb, thb,
                                          gam, bet, mea, var, linw, linb,
                                          WT, coef, mode, chunk, offs);
    gasc_k<<<2 * NGB, 256, 0, stream>>>(x, WT, coef, mode, hb, chunk, offs, bsrc, cnt);
    gat_out_k<<<(NN * 64 + 255) / 256, 256, 0, stream>>>(hb, cnt, bsrc, gcnb, coef, mode, d_out);
}